// Round 1
// baseline (218.303 us; speedup 1.0000x reference)
//
#include <hip/hip_runtime.h>
#include <math.h>

constexpr int B = 4;
constexpr int N = 8192;
constexpr int KNN = 8;
constexpr int GRID1 = 16;                      // 16^3 Morton cells
constexpr int NCELL = GRID1 * GRID1 * GRID1;   // 4096
constexpr int GSIZE = 16;                      // points per group
constexpr int NGRP = N / GSIZE;                // 512 groups per (cloud,batch)
constexpr int QPB = 64;                        // queries per wave (one per lane)
constexpr int WAVES = 8;                       // waves per block

// Insert tv into sorted ascending d[0..7], keeping the smallest 8 sorted.
// Exact identity: d'[0] = min(d0,tv); d'[i] = med3(d[i-1], d[i], tv).
__device__ __forceinline__ void insert8(float (&d)[KNN], float tv) {
  float n0 = fminf(d[0], tv);
  float n1 = __builtin_amdgcn_fmed3f(d[0], d[1], tv);
  float n2 = __builtin_amdgcn_fmed3f(d[1], d[2], tv);
  float n3 = __builtin_amdgcn_fmed3f(d[2], d[3], tv);
  float n4 = __builtin_amdgcn_fmed3f(d[3], d[4], tv);
  float n5 = __builtin_amdgcn_fmed3f(d[4], d[5], tv);
  float n6 = __builtin_amdgcn_fmed3f(d[5], d[6], tv);
  float n7 = __builtin_amdgcn_fmed3f(d[6], d[7], tv);
  d[0] = n0; d[1] = n1; d[2] = n2; d[3] = n3;
  d[4] = n4; d[5] = n5; d[6] = n6; d[7] = n7;
}

__device__ __forceinline__ int morton3(int x, int y, int z) {
  int m = 0;
#pragma unroll
  for (int b = 0; b < 4; ++b)
    m |= (((x >> b) & 1) << (3 * b + 2)) | (((y >> b) & 1) << (3 * b + 1)) |
         (((z >> b) & 1) << (3 * b + 0));
  return m;
}

// Counting sort of each (cloud,batch) by Morton cell. One block per cloud-batch.
// Also packs w = |p|^2/2 and zeroes the output accumulator.
__global__ __launch_bounds__(1024) void sort_kernel(
    const float* __restrict__ src, const float* __restrict__ tgt,
    const float* __restrict__ flow, float4* __restrict__ pred_s,
    float4* __restrict__ tgt_s, float* __restrict__ out) {
  int cb = blockIdx.x;            // 0..7: cloud = cb>>2, batch = cb&3
  int cloud = cb >> 2, batch = cb & 3;
  int tid = threadIdx.x;
  if (cb == 0 && tid == 0) out[0] = 0.0f;

  __shared__ int hist[NCELL];     // 16 KB
  for (int i = tid; i < NCELL; i += 1024) hist[i] = 0;
  __syncthreads();

  const float* __restrict__ bp = (cloud == 0 ? src : tgt) + batch * N * 3;
  const float* __restrict__ bf = flow + batch * N * 3;

  float4 pt[8];
  int cell[8];
#pragma unroll
  for (int k = 0; k < 8; ++k) {
    int i = k * 1024 + tid;
    float x = bp[3 * i + 0], y = bp[3 * i + 1], z = bp[3 * i + 2];
    if (cloud == 0) { x += bf[3 * i + 0]; y += bf[3 * i + 1]; z += bf[3 * i + 2]; }
    pt[k] = make_float4(x, y, z, 0.5f * (x * x + y * y + z * z));
    int cx = (int)fminf(fmaxf((x + 4.0f) * 2.0f, 0.0f), 15.0f);
    int cy = (int)fminf(fmaxf((y + 4.0f) * 2.0f, 0.0f), 15.0f);
    int cz = (int)fminf(fmaxf((z + 4.0f) * 2.0f, 0.0f), 15.0f);
    cell[k] = morton3(cx, cy, cz);
    atomicAdd(&hist[cell[k]], 1);
  }
  __syncthreads();

  // Exclusive scan of 4096 bins by wave 0: 64 bins serial per lane + wave scan.
  if (tid < 64) {
    int base = tid * 64, s = 0;
#pragma unroll 1
    for (int i = 0; i < 64; ++i) { int v = hist[base + i]; hist[base + i] = s; s += v; }
    int t = s;
    for (int off = 1; off < 64; off <<= 1) {
      int u = __shfl_up(t, off, 64);
      if (tid >= off) t += u;
    }
    int excl = t - s;
#pragma unroll 1
    for (int i = 0; i < 64; ++i) hist[base + i] += excl;
  }
  __syncthreads();

  float4* __restrict__ dst = (cloud == 0 ? pred_s : tgt_s) + batch * N;
#pragma unroll
  for (int k = 0; k < 8; ++k) {
    int pos = atomicAdd(&hist[cell[k]], 1);   // base += running count -> slot
    dst[pos] = pt[k];
  }
}

// Per-group AABB over 16 consecutive sorted points. 4096 groups total.
__global__ __launch_bounds__(256) void aabb_kernel(
    const float4* __restrict__ pred_s, const float4* __restrict__ tgt_s,
    float4* __restrict__ aabb) {
  int g = blockIdx.x * 256 + threadIdx.x;     // 0..4095
  int cb = g >> 9;                            // g / NGRP
  int cloud = cb >> 2, batch = cb & 3;
  int lg = g & (NGRP - 1);
  const float4* __restrict__ sp =
      (cloud == 0 ? pred_s : tgt_s) + batch * N + lg * GSIZE;
  float lx = INFINITY, ly = INFINITY, lz = INFINITY;
  float hx = -INFINITY, hy = -INFINITY, hz = -INFINITY;
#pragma unroll
  for (int j = 0; j < GSIZE; ++j) {
    float4 p = sp[j];
    lx = fminf(lx, p.x); ly = fminf(ly, p.y); lz = fminf(lz, p.z);
    hx = fmaxf(hx, p.x); hy = fmaxf(hy, p.y); hz = fmaxf(hz, p.z);
  }
  aabb[2 * g + 0] = make_float4(lx, ly, lz, 0.0f);
  aabb[2 * g + 1] = make_float4(hx, hy, hz, 0.0f);
}

// Block = 8 waves x 64 lanes; lane = one sorted query. Wave w owns the
// interleaved group class {g : g % 8 == w} (64 groups). Seeds top-8 from 2
// rank-matched groups, AABB-tests the rest against the seeded threshold
// (exact pruning: skipped candidate has dist >= boxMin >= thr >= final d7),
// then processes only passing groups. Merge phase identical to the verified
// brute-force version.
__global__ __launch_bounds__(512, 8) void chamfer_kernel(
    const float4* __restrict__ pred_s, const float4* __restrict__ tgt_s,
    const float4* __restrict__ aabb, float* __restrict__ out) {
  int blk = blockIdx.x;           // 1024 blocks
  int dir = blk >> 9;             // 0: pred->tgt, 1: tgt->pred
  int batch = (blk >> 7) & 3;
  int chunk = blk & 127;          // 128 chunks of 64 sorted queries
  const float4* __restrict__ qarr = (dir == 0 ? pred_s : tgt_s) + batch * N;
  const float4* __restrict__ parr = (dir == 0 ? tgt_s : pred_s) + batch * N;
  int ccb = (dir == 0 ? 4 + batch : batch);       // candidate cloud-batch
  const float4* __restrict__ gb = aabb + ccb * (2 * NGRP);

  int lane = threadIdx.x & 63;
  int wv = __builtin_amdgcn_readfirstlane(threadIdx.x >> 6);  // uniform wave id

  float4 q = qarr[chunk * QPB + lane];
  float nqx = -q.x, nqy = -q.y, nqz = -q.z;
  float two_qw = 2.0f * q.w;      // |q|^2

  float d[KNN];
#pragma unroll
  for (int i = 0; i < KNN; ++i) d[i] = INFINITY;

  auto process_group = [&](int g) {
    const float4* __restrict__ gp = parr + g * GSIZE;   // wave-uniform address
#pragma unroll
    for (int j = 0; j < GSIZE; ++j) {
      float4 p = gp[j];
      float tv = __builtin_fmaf(nqx, p.x, __builtin_fmaf(nqy, p.y,
                 __builtin_fmaf(nqz, p.z, p.w)));
      insert8(d, tv);
    }
  };

  // Seeds: 2 groups in own residue class near the query block's rank.
  int g1 = ((chunk * 4) & ~7) + wv;
  int g2 = (g1 + 8 < NGRP) ? g1 + 8 : g1 - 8;
  process_group(g1);
  process_group(g2);

  // Pass 1: branchless AABB tests (d[] is fixed here, so thr hoists).
  // 1e-5 relative margin keeps fp rounding strictly conservative.
  float thr = __builtin_fmaf(2.0f, d[KNN - 1], two_qw) * 1.00001f + 1e-6f;
  unsigned long long mask = 0;
  for (int gi = 0; gi < NGRP / 8; ++gi) {       // 64 tests
    int g = gi * 8 + wv;
    float4 lo = gb[2 * g + 0];
    float4 hi = gb[2 * g + 1];
    float dx = fmaxf(fmaxf(lo.x - q.x, q.x - hi.x), 0.0f);
    float dy = fmaxf(fmaxf(lo.y - q.y, q.y - hi.y), 0.0f);
    float dz = fmaxf(fmaxf(lo.z - q.z, q.z - hi.z), 0.0f);
    float md = __builtin_fmaf(dx, dx, __builtin_fmaf(dy, dy, dz * dz));
    mask |= (unsigned long long)(__ballot(md < thr) != 0) << gi;
  }
  // Never re-process seed groups (double-insert would corrupt the merge).
  mask &= ~((1ull << ((g1 - wv) >> 3)) | (1ull << ((g2 - wv) >> 3)));

  // Pass 2: process surviving groups only.
  while (mask) {
    int gi = __builtin_ctzll(mask);
    mask &= mask - 1;
    process_group(gi * 8 + wv);
  }

  // Merge 8 waves' sorted top-8 per query through LDS (stride 9).
  __shared__ float part[WAVES][QPB][KNN + 1];   // 18 KB
#pragma unroll
  for (int i = 0; i < KNN; ++i) part[wv][lane][i] = d[i];
  __syncthreads();

  if (wv == 0) {
    float m[KNN];
#pragma unroll
    for (int i = 0; i < KNN; ++i) m[i] = part[0][lane][i];
    for (int s = 1; s < WAVES; ++s) {
#pragma unroll
      for (int i = 0; i < KNN; ++i) insert8(m, part[s][lane][i]);
    }
    float s_ = 0.0f;
#pragma unroll
    for (int i = 0; i < KNN; ++i) {
      float d2 = fmaxf(__builtin_fmaf(2.0f, m[i], two_qw), 0.0f);
      s_ += sqrtf(d2);
    }
    float val = s_ * (1.0f / KNN);
    for (int off = 32; off; off >>= 1) val += __shfl_down(val, off, 64);
    if (lane == 0) atomicAdd(out, val * (1.0f / (B * N)));
  }
}

extern "C" void kernel_launch(void* const* d_in, const int* in_sizes, int n_in,
                              void* d_out, int out_size, void* d_ws, size_t ws_size,
                              hipStream_t stream) {
  const float* src = (const float*)d_in[0];
  const float* tgt = (const float*)d_in[1];
  const float* flow = (const float*)d_in[2];
  float* out = (float*)d_out;
  float4* pred_s = (float4*)d_ws;               // 512 KB
  float4* tgt_s = pred_s + B * N;               // 512 KB
  float4* aabb = tgt_s + B * N;                 // 8192 float4 = 128 KB

  sort_kernel<<<8, 1024, 0, stream>>>(src, tgt, flow, pred_s, tgt_s, out);
  aabb_kernel<<<(2 * B * NGRP) / 256, 256, 0, stream>>>(pred_s, tgt_s, aabb);
  chamfer_kernel<<<2 * B * (N / QPB), 512, 0, stream>>>(pred_s, tgt_s, aabb, out);
}

// Round 2
// 164.139 us; speedup vs baseline: 1.3300x; 1.3300x over previous
//
#include <hip/hip_runtime.h>
#include <math.h>

constexpr int B = 4;
constexpr int N = 8192;
constexpr int KNN = 8;
constexpr int GRID1 = 16;                      // 16^3 Morton cells
constexpr int NCELL = GRID1 * GRID1 * GRID1;   // 4096
constexpr int GSIZE = 16;                      // points per group
constexpr int NGRP = N / GSIZE;                // 512 groups per (cloud,batch)
constexpr int QPB = 64;                        // queries per wave (one per lane)
constexpr int WAVES = 8;                       // waves per block
constexpr int NCB = 2 * B;                     // cloud-batches

// Insert tv into sorted ascending d[0..7], keeping the smallest 8 sorted.
// Exact identity: d'[0] = min(d0,tv); d'[i] = med3(d[i-1], d[i], tv).
__device__ __forceinline__ void insert8(float (&d)[KNN], float tv) {
  float n0 = fminf(d[0], tv);
  float n1 = __builtin_amdgcn_fmed3f(d[0], d[1], tv);
  float n2 = __builtin_amdgcn_fmed3f(d[1], d[2], tv);
  float n3 = __builtin_amdgcn_fmed3f(d[2], d[3], tv);
  float n4 = __builtin_amdgcn_fmed3f(d[3], d[4], tv);
  float n5 = __builtin_amdgcn_fmed3f(d[4], d[5], tv);
  float n6 = __builtin_amdgcn_fmed3f(d[5], d[6], tv);
  float n7 = __builtin_amdgcn_fmed3f(d[6], d[7], tv);
  d[0] = n0; d[1] = n1; d[2] = n2; d[3] = n3;
  d[4] = n4; d[5] = n5; d[6] = n6; d[7] = n7;
}

__device__ __forceinline__ int morton3(int x, int y, int z) {
  int m = 0;
#pragma unroll
  for (int b = 0; b < 4; ++b)
    m |= (((x >> b) & 1) << (3 * b + 2)) | (((y >> b) & 1) << (3 * b + 1)) |
         (((z >> b) & 1) << (3 * b + 0));
  return m;
}

__device__ __forceinline__ int point_cell(float x, float y, float z) {
  int cx = (int)fminf(fmaxf((x + 4.0f) * 2.0f, 0.0f), 15.0f);
  int cy = (int)fminf(fmaxf((y + 4.0f) * 2.0f, 0.0f), 15.0f);
  int cz = (int)fminf(fmaxf((z + 4.0f) * 2.0f, 0.0f), 15.0f);
  return morton3(cx, cy, cz);
}

// ---- parallel counting-sort pipeline (4 small kernels, all wide-grid) ----

__global__ __launch_bounds__(1024) void zero_kernel(int* __restrict__ hist,
                                                    float* __restrict__ out) {
  int i = blockIdx.x * 1024 + threadIdx.x;   // grid 32 -> 32768 ints
  if (i == 0) out[0] = 0.0f;
  hist[i] = 0;
}

__global__ __launch_bounds__(1024) void hist_kernel(
    const float* __restrict__ src, const float* __restrict__ tgt,
    const float* __restrict__ flow, int* __restrict__ hist,
    unsigned short* __restrict__ cellid) {
  int gid = blockIdx.x * 1024 + threadIdx.x;   // grid 64 -> 65536 points
  int cb = gid >> 13;
  int idx = gid & (N - 1);
  int cloud = cb >> 2, batch = cb & 3;
  const float* __restrict__ bp = (cloud == 0 ? src : tgt) + batch * N * 3;
  float x = bp[3 * idx + 0], y = bp[3 * idx + 1], z = bp[3 * idx + 2];
  if (cloud == 0) {
    const float* __restrict__ bf = flow + batch * N * 3;
    x += bf[3 * idx + 0]; y += bf[3 * idx + 1]; z += bf[3 * idx + 2];
  }
  int cell = point_cell(x, y, z);
  cellid[gid] = (unsigned short)cell;
  atomicAdd(&hist[cb * NCELL + cell], 1);
}

// Exclusive scan of each cb's 4096 bins: one wave per cb.
__global__ __launch_bounds__(64) void scan_kernel(int* __restrict__ hist) {
  int lane = threadIdx.x;
  int* h = hist + blockIdx.x * NCELL;
  int base = lane * 64, s = 0;
#pragma unroll 1
  for (int i = 0; i < 64; ++i) { int v = h[base + i]; h[base + i] = s; s += v; }
  int t = s;
  for (int off = 1; off < 64; off <<= 1) {
    int u = __shfl_up(t, off, 64);
    if (lane >= off) t += u;
  }
  int excl = t - s;
#pragma unroll 1
  for (int i = 0; i < 64; ++i) h[base + i] += excl;
}

__global__ __launch_bounds__(1024) void scatter_kernel(
    const float* __restrict__ src, const float* __restrict__ tgt,
    const float* __restrict__ flow, int* __restrict__ hist,
    const unsigned short* __restrict__ cellid, float4* __restrict__ pred_s,
    float4* __restrict__ tgt_s) {
  int gid = blockIdx.x * 1024 + threadIdx.x;   // grid 64
  int cb = gid >> 13;
  int idx = gid & (N - 1);
  int cloud = cb >> 2, batch = cb & 3;
  const float* __restrict__ bp = (cloud == 0 ? src : tgt) + batch * N * 3;
  float x = bp[3 * idx + 0], y = bp[3 * idx + 1], z = bp[3 * idx + 2];
  if (cloud == 0) {
    const float* __restrict__ bf = flow + batch * N * 3;
    x += bf[3 * idx + 0]; y += bf[3 * idx + 1]; z += bf[3 * idx + 2];
  }
  int cell = cellid[gid];
  int pos = atomicAdd(&hist[cb * NCELL + cell], 1);
  float4* __restrict__ dst = (cloud == 0 ? pred_s : tgt_s) + batch * N;
  dst[pos] = make_float4(x, y, z, 0.5f * (x * x + y * y + z * z));
}

// Per-group AABB over 16 consecutive sorted points. 4096 groups total.
__global__ __launch_bounds__(256) void aabb_kernel(
    const float4* __restrict__ pred_s, const float4* __restrict__ tgt_s,
    float4* __restrict__ aabb) {
  int g = blockIdx.x * 256 + threadIdx.x;     // 0..4095
  int cb = g >> 9;
  int cloud = cb >> 2, batch = cb & 3;
  int lg = g & (NGRP - 1);
  const float4* __restrict__ sp =
      (cloud == 0 ? pred_s : tgt_s) + batch * N + lg * GSIZE;
  float lx = INFINITY, ly = INFINITY, lz = INFINITY;
  float hx = -INFINITY, hy = -INFINITY, hz = -INFINITY;
#pragma unroll
  for (int j = 0; j < GSIZE; ++j) {
    float4 p = sp[j];
    lx = fminf(lx, p.x); ly = fminf(ly, p.y); lz = fminf(lz, p.z);
    hx = fmaxf(hx, p.x); hy = fmaxf(hy, p.y); hz = fmaxf(hz, p.z);
  }
  aabb[2 * g + 0] = make_float4(lx, ly, lz, 0.0f);
  aabb[2 * g + 1] = make_float4(hx, hy, hz, 0.0f);
}

// Block = 8 waves x 64 lanes; lane = one sorted query. Wave w owns group
// residue class {g : g % 8 == w}. Best-first sweep: zigzag outward from the
// rank-matched group, test each box against the CURRENT per-lane threshold,
// process only if any lane passes, tighten thr immediately. First group
// auto-passes (thr=INF) and self-seeds. Pruning is exact: box-min is a lower
// bound on dist^2 and thr is monotone non-increasing, so a skipped candidate
// can never enter the final top-8 (1e-5 relative margin covers fp rounding).
__global__ __launch_bounds__(512, 8) void chamfer_kernel(
    const float4* __restrict__ pred_s, const float4* __restrict__ tgt_s,
    const float4* __restrict__ aabb, float* __restrict__ out) {
  int blk = blockIdx.x;           // 1024 blocks
  int dir = blk >> 9;             // 0: pred->tgt, 1: tgt->pred
  int batch = (blk >> 7) & 3;
  int chunk = blk & 127;          // 128 chunks of 64 sorted queries
  const float4* __restrict__ qarr = (dir == 0 ? pred_s : tgt_s) + batch * N;
  const float4* __restrict__ parr = (dir == 0 ? tgt_s : pred_s) + batch * N;
  int ccb = (dir == 0 ? 4 + batch : batch);
  const float4* __restrict__ gb = aabb + ccb * (2 * NGRP);

  int lane = threadIdx.x & 63;
  int wv = __builtin_amdgcn_readfirstlane(threadIdx.x >> 6);

  __shared__ float4 boxes[2 * NGRP];            // 16 KB, shared by all waves
  __shared__ float part[WAVES][QPB][KNN + 1];   // 18 KB, slice merge

  for (int i = threadIdx.x; i < 2 * NGRP; i += 512) boxes[i] = gb[i];

  float4 q = qarr[chunk * QPB + lane];
  float nqx = -q.x, nqy = -q.y, nqz = -q.z;
  float two_qw = 2.0f * q.w;      // |q|^2

  float d[KNN];
#pragma unroll
  for (int i = 0; i < KNN; ++i) d[i] = INFINITY;
  float thr = INFINITY;

  __syncthreads();

  // Rank-matched start group index within this wave's residue class.
  int tc = (chunk * 4 + 6 - wv) >> 3;
  tc = max(0, min(63, tc));

  auto step = [&](int t) {
    int g = t * 8 + wv;                          // wave-uniform
    float4 lo = boxes[2 * g + 0];                // broadcast ds_read
    float4 hi = boxes[2 * g + 1];
    float dx = fmaxf(fmaxf(lo.x - q.x, q.x - hi.x), 0.0f);
    float dy = fmaxf(fmaxf(lo.y - q.y, q.y - hi.y), 0.0f);
    float dz = fmaxf(fmaxf(lo.z - q.z, q.z - hi.z), 0.0f);
    float md = __builtin_fmaf(dx, dx, __builtin_fmaf(dy, dy, dz * dz));
    if (__ballot(md < thr)) {
      const float4* __restrict__ gp = parr + g * GSIZE;  // uniform -> s_load
#pragma unroll
      for (int j = 0; j < GSIZE; ++j) {
        float4 p = gp[j];
        float tv = __builtin_fmaf(nqx, p.x, __builtin_fmaf(nqy, p.y,
                   __builtin_fmaf(nqz, p.z, p.w)));
        insert8(d, tv);
      }
      thr = __builtin_fmaf(2.0f, d[KNN - 1], two_qw) * 1.00001f + 1e-6f;
    }
  };

  for (int t = tc; t < 64; ++t) step(t);
  for (int t = tc - 1; t >= 0; --t) step(t);

  // Merge 8 waves' sorted top-8 per query through LDS (stride 9).
#pragma unroll
  for (int i = 0; i < KNN; ++i) part[wv][lane][i] = d[i];
  __syncthreads();

  if (wv == 0) {
    float m[KNN];
#pragma unroll
    for (int i = 0; i < KNN; ++i) m[i] = part[0][lane][i];
    for (int s = 1; s < WAVES; ++s) {
#pragma unroll
      for (int i = 0; i < KNN; ++i) insert8(m, part[s][lane][i]);
    }
    float s_ = 0.0f;
#pragma unroll
    for (int i = 0; i < KNN; ++i) {
      float d2 = fmaxf(__builtin_fmaf(2.0f, m[i], two_qw), 0.0f);
      s_ += sqrtf(d2);
    }
    float val = s_ * (1.0f / KNN);
    for (int off = 32; off; off >>= 1) val += __shfl_down(val, off, 64);
    if (lane == 0) atomicAdd(out, val * (1.0f / (B * N)));
  }
}

extern "C" void kernel_launch(void* const* d_in, const int* in_sizes, int n_in,
                              void* d_out, int out_size, void* d_ws, size_t ws_size,
                              hipStream_t stream) {
  const float* src = (const float*)d_in[0];
  const float* tgt = (const float*)d_in[1];
  const float* flow = (const float*)d_in[2];
  float* out = (float*)d_out;
  float4* pred_s = (float4*)d_ws;                        // 512 KB
  float4* tgt_s = pred_s + B * N;                        // 512 KB
  float4* aabb = tgt_s + B * N;                          // 128 KB
  int* hist = (int*)(aabb + NCB * 2 * NGRP);             // 128 KB
  unsigned short* cellid = (unsigned short*)(hist + NCB * NCELL);  // 128 KB

  zero_kernel<<<(NCB * NCELL) / 1024, 1024, 0, stream>>>(hist, out);
  hist_kernel<<<(NCB * N) / 1024, 1024, 0, stream>>>(src, tgt, flow, hist, cellid);
  scan_kernel<<<NCB, 64, 0, stream>>>(hist);
  scatter_kernel<<<(NCB * N) / 1024, 1024, 0, stream>>>(src, tgt, flow, hist,
                                                        cellid, pred_s, tgt_s);
  aabb_kernel<<<(NCB * NGRP) / 256, 256, 0, stream>>>(pred_s, tgt_s, aabb);
  chamfer_kernel<<<2 * B * (N / QPB), 512, 0, stream>>>(pred_s, tgt_s, aabb, out);
}